// Round 18
// baseline (329.658 us; speedup 1.0000x reference)
//
#include <hip/hip_runtime.h>
#include <stdint.h>

// LinearBin: out = x @ sign(W)^T + bias   (B=131072, IN=OUT=512, fp32)
// v18: producer/consumer wave specialization. 768-thread blocks, grid=256
//      (1/CU): 8 consumer waves (v8 K-loop, 56 VGPR + 64 AGPR, never stage)
//      + 4 producer waves (load+cvt+ds_write, ~80 VGPR, never accumulate).
//      2x64KB LDS double buffer, NS=8 strips/block. One raw s_barrier per
//      strip; producer lgkmcnt(0) only -- no vmcnt(0) drain anywhere.
//      Per-wave vmcnt => producer waits never stall consumers and vice versa.

#define BATCH   131072
#define IN_F    512
#define OUT_F   512
#define BM      64
#define NS      8             // strips per block
#define NKT     32            // K-steps of 16

using f32x4  = __attribute__((ext_vector_type(4))) float;
using f32x16 = __attribute__((ext_vector_type(16))) float;
using short8 = __attribute__((ext_vector_type(8))) short;
using usv8   = __attribute__((ext_vector_type(8))) unsigned short;
using u32    = uint32_t;

// ---------------- prep: binarize W into 32x32x16-fragment-major bf16 --------
// (verified r6/r8)  wf[((kt*16+nf)*64+l)*8+j] = sign(W[nf*32+(l&31)][kt*16+(l>>5)*8+j])
__global__ void prep_w(const float* __restrict__ W, unsigned short* __restrict__ wf) {
    int t = blockIdx.x * blockDim.x + threadIdx.x; // 32768 threads
    int l  = t & 63;
    int nf = (t >> 6) & 15;
    int kt = t >> 10;
    int n = nf * 32 + (l & 31);
    int k = kt * 16 + ((l >> 5) << 3);
    const float* src = W + (size_t)n * IN_F + k;
    f32x4 w0 = *(const f32x4*)(src);
    f32x4 w1 = *(const f32x4*)(src + 4);
    usv8 o;
#pragma unroll
    for (int j = 0; j < 4; ++j) {
        o[j]     = (w0[j] >= 0.0f) ? 0x3F80u : 0xBF80u; // +1.0 / -1.0 bf16
        o[j + 4] = (w1[j] >= 0.0f) ? 0x3F80u : 0xBF80u;
    }
    *(usv8*)(wf + (size_t)t * 8) = o;
}

__device__ __forceinline__ u32 cvt2(float a, float b) {
    u32 r;
    asm("v_cvt_pk_bf16_f32 %0, %1, %2" : "=v"(r) : "v"(a), "v"(b));
    return r;
}

// ---------------- GEMM: producer/consumer specialized ----------------
__global__ __launch_bounds__(768, 1) void gemm_bin(
    const float* __restrict__ X, const unsigned short* __restrict__ WF,
    const float* __restrict__ bias, float* __restrict__ out) {

    // two buffers: [buf][64 rows][512 bf16]; slot k (16B) of row r at byte
    // (16k)^((r&7)<<4), holding floats 8k..8k+7 as bf16. 128KB total.
    __shared__ __align__(16) unsigned short lds[2][BM * IN_F];

    const int tid  = threadIdx.x;
    const int lane = tid & 63;
    const int wv   = tid >> 6;                 // 0..7 consumers, 8..11 producers
    const size_t m0b = (size_t)blockIdx.x * (NS * BM);   // grid = 256

    // ---- prologue: threads 0..511 stage strip 0 into buf 0 (v8 geometry) ----
    if (tid < 512) {
        const int sr = tid >> 3, sg = tid & 7, swz = (sr & 7) << 4;
        const float* xr = X + (m0b + sr) * IN_F;
        char* lrow = (char*)lds[0] + sr * 1024;
#pragma unroll
        for (int p = 0; p < 8; ++p) {
            const int f0 = sg * 8 + p * 64;
            f32x4 a = *(const f32x4*)(xr + f0);
            f32x4 b = *(const f32x4*)(xr + f0 + 4);
            union { u32 w[4]; usv8 v; } pk;
            pk.w[0] = cvt2(a[0], a[1]); pk.w[1] = cvt2(a[2], a[3]);
            pk.w[2] = cvt2(b[0], b[1]); pk.w[3] = cvt2(b[2], b[3]);
            *(usv8*)(lrow + ((sg * 16 + p * 128) ^ swz)) = pk.v;
        }
    }
    __syncthreads();

    if (wv < 8) {
        // ================= CONSUMER: v8 K-loop, no staging ever =============
        const int arow  = (lane & 31) * 1024;
        const int ak4   = (lane >> 5) << 4;
        const int aswz  = (lane & 7) << 4;
        const short8* wb = (const short8*)(WF) + ((size_t)(wv * 2) * 64 + lane);
        const float bv0 = bias[wv * 64 + (lane & 31)];
        const float bv1 = bias[wv * 64 + 32 + (lane & 31)];
        const int c     = lane & 31;
        const int rbase = (lane >> 5) << 2;

#define LDA(dst, kt_)                                                          \
    {                                                                          \
        const int koff_ = ((kt_) * 32 + ak4) ^ aswz;                           \
        dst[0] = *(const short8*)(lptr + arow + koff_);                        \
        dst[1] = *(const short8*)(lptr + arow + 32768 + koff_);                \
    }
#define LDB(dst, kt_)                                                          \
    {                                                                          \
        _Pragma("unroll")                                                      \
        for (int fn = 0; fn < 2; ++fn)                                         \
            dst[fn] = wb[(kt_) * 1024 + fn * 64];                              \
    }

#pragma unroll 1
        for (int s = 0; s < NS; ++s) {
            const char* lptr = (const char*)lds[s & 1];
            f32x16 acc[2][2];
#pragma unroll
            for (int r = 0; r < 16; ++r) {
                acc[0][0][r] = bv0; acc[0][1][r] = bv1;
                acc[1][0][r] = bv0; acc[1][1][r] = bv1;
            }
            short8 af[2][2], bf[2][2];
            LDA(af[0], 0);
            LDB(bf[0], 0);
            LDB(bf[1], 1);
#pragma unroll
            for (int kt = 0; kt < NKT; ++kt) {
                const int cur = kt & 1;
                if (kt < NKT - 1) LDA(af[cur ^ 1], kt + 1);
#pragma unroll
                for (int rg = 0; rg < 2; ++rg)
#pragma unroll
                    for (int fn = 0; fn < 2; ++fn)
                        acc[rg][fn] = __builtin_amdgcn_mfma_f32_32x32x16_bf16(
                            af[cur][rg], bf[cur][fn], acc[rg][fn], 0, 0, 0);
                if (kt < NKT - 2) LDB(bf[cur], kt + 2);
            }
            // fire-and-forget stores; drain under next strip
            const size_t ms = m0b + (size_t)s * BM;
#pragma unroll
            for (int rg = 0; rg < 2; ++rg)
#pragma unroll
                for (int fn = 0; fn < 2; ++fn)
#pragma unroll
                    for (int r = 0; r < 16; ++r) {
                        const int row = rg * 32 + (r & 3) + 8 * (r >> 2) + rbase;
                        out[(ms + row) * OUT_F + wv * 64 + fn * 32 + c] =
                            acc[rg][fn][r];
                    }
            __builtin_amdgcn_sched_barrier(0);
            __builtin_amdgcn_s_barrier();
            __builtin_amdgcn_sched_barrier(0);
        }
#undef LDA
#undef LDB
    } else {
        // ================= PRODUCER: stage strip s+1, no acc ever ===========
        const int pt  = tid - 512;            // 0..255
        const int r   = pt >> 2;              // row 0..63
        const int q   = pt & 3;               // 128-float quarter
        const int swz = (r & 7) << 4;

#pragma unroll 1
        for (int s = 0; s < NS; ++s) {
            if (s + 1 < NS) {
                const float* xr = X + (m0b + (size_t)(s + 1) * BM + r) * IN_F + q * 128;
                char* lrow = (char*)lds[(s + 1) & 1] + r * 1024;
#pragma unroll
                for (int h = 0; h < 2; ++h) {
                    f32x4 v[16];
#pragma unroll
                    for (int i = 0; i < 16; ++i)
                        v[i] = *(const f32x4*)(xr + h * 64 + i * 4);
#pragma unroll
                    for (int j = 0; j < 8; ++j) {
                        union { u32 w[4]; usv8 vv; } pk;
                        pk.w[0] = cvt2(v[2 * j][0], v[2 * j][1]);
                        pk.w[1] = cvt2(v[2 * j][2], v[2 * j][3]);
                        pk.w[2] = cvt2(v[2 * j + 1][0], v[2 * j + 1][1]);
                        pk.w[3] = cvt2(v[2 * j + 1][2], v[2 * j + 1][3]);
                        // slot k = 16q + 8h + j
                        *(usv8*)(lrow + ((16 * (16 * q + 8 * h + j)) ^ swz)) = pk.vv;
                    }
                }
                asm volatile("s_waitcnt lgkmcnt(0)" ::: "memory");
            }
            __builtin_amdgcn_sched_barrier(0);
            __builtin_amdgcn_s_barrier();
            __builtin_amdgcn_sched_barrier(0);
        }
    }
}

extern "C" void kernel_launch(void* const* d_in, const int* in_sizes, int n_in,
                              void* d_out, int out_size, void* d_ws, size_t ws_size,
                              hipStream_t stream) {
    const float* X    = (const float*)d_in[0];
    const float* W    = (const float*)d_in[1];
    const float* bias = (const float*)d_in[2];
    float* o          = (float*)d_out;
    unsigned short* wf = (unsigned short*)d_ws; // 512KB fragment-major binarized W

    hipLaunchKernelGGL(prep_w, dim3(128), dim3(256), 0, stream, W, wf);
    hipLaunchKernelGGL(gemm_bin, dim3(BATCH / (BM * NS)), dim3(768), 0, stream,
                       X, wf, bias, o);
}

// Round 19
// 138.756 us; speedup vs baseline: 2.3758x; 2.3758x over previous
//
#include <hip/hip_runtime.h>
#include <stdint.h>

// LinearBin: out = x @ sign(W)^T + bias   (B=131072, IN=OUT=512, fp32)
// v19: v12 (best, 136.7us) + two local fixes, register-neutral:
//      (1) ISSUE_DMA(ck+2) moved AFTER the in-loop LDBs -> in-chunk B
//          consumption no longer forces the fresh DMA to retire (vmcnt is
//          a per-wave FIFO; v12 stalled ~500cy every chunk on this).
//      (2) 16-slot XOR swizzle (v13/v15-verified, 0 conflicts) replaces
//          v12's conflicted 8-slot fp32 form, both DMA-source and read side.
//      Same 4x16KB fp32 ring, cvt_pk at fragment-read, 8 waves x (64x64),
//      64KB LDS, 2 blocks/CU, v12 epilogue.

#define BATCH   131072
#define IN_F    512
#define OUT_F   512
#define BM      64
#define NCH     8             // K-chunks of 64 floats (4 mfma k-steps each)
#define BUFB    16384         // bytes per ring buffer

using f32x4  = __attribute__((ext_vector_type(4))) float;
using f32x16 = __attribute__((ext_vector_type(16))) float;
using short8 = __attribute__((ext_vector_type(8))) short;
using usv8   = __attribute__((ext_vector_type(8))) unsigned short;
using u32    = uint32_t;

// ---------------- prep: binarize W into 32x32x16-fragment-major bf16 --------
// (verified r6/r8)  wf[((kt*16+nf)*64+l)*8+j] = sign(W[nf*32+(l&31)][kt*16+(l>>5)*8+j])
__global__ void prep_w(const float* __restrict__ W, unsigned short* __restrict__ wf) {
    int t = blockIdx.x * blockDim.x + threadIdx.x; // 32768 threads
    int l  = t & 63;
    int nf = (t >> 6) & 15;
    int kt = t >> 10;
    int n = nf * 32 + (l & 31);
    int k = kt * 16 + ((l >> 5) << 3);
    const float* src = W + (size_t)n * IN_F + k;
    f32x4 w0 = *(const f32x4*)(src);
    f32x4 w1 = *(const f32x4*)(src + 4);
    usv8 o;
#pragma unroll
    for (int j = 0; j < 4; ++j) {
        o[j]     = (w0[j] >= 0.0f) ? 0x3F80u : 0xBF80u; // +1.0 / -1.0 bf16
        o[j + 4] = (w1[j] >= 0.0f) ? 0x3F80u : 0xBF80u;
    }
    *(usv8*)(wf + (size_t)t * 8) = o;
}

// ---------------- GEMM ----------------
__global__ __launch_bounds__(512, 4) void gemm_bin(
    const float* __restrict__ X, const unsigned short* __restrict__ WF,
    const float* __restrict__ bias, float* __restrict__ out) {

    // ring of 4 fp32 chunks: [64 rows][256B], 16B slots XOR-swizzled by row&15
    __shared__ __align__(16) char smem[4 * BUFB];   // 64KB -> 2 blocks/CU

    const int tid  = threadIdx.x;
    const int lane = tid & 63;
    const int wv   = tid >> 6;              // 0..7 -> 64-col strip
    const int m0   = blockIdx.x * BM;       // grid = 2048

    // ---- DMA source geometry (2 x 16B per thread per chunk; v13-verified) ----
    // lin LDS off = wv*1024 + lane*16 -> row = wv*4 + (lane>>4), slot = lane&15
    // content: LDS[r][s] = x[m0+r][ck*64 + 4*(s ^ (r&15))]
    const int dr   = wv * 4 + (lane >> 4);
    const int ds4  = ((lane & 15) ^ (dr & 15)) << 2;
    const float* src0 = X + (size_t)(m0 + dr) * IN_F + ds4;
    const float* src1 = src0 + (size_t)32 * IN_F;   // (dr+32)&15 == dr&15

#define ISSUE_DMA(ck_)                                                         \
    {                                                                          \
        char* b_ = smem + ((ck_) & 3) * BUFB + wv * 1024;                      \
        __builtin_amdgcn_global_load_lds(                                      \
            (const __attribute__((address_space(1))) void*)(src0 + (ck_) * 64),\
            (__attribute__((address_space(3))) void*)(b_), 16, 0, 0);          \
        __builtin_amdgcn_global_load_lds(                                      \
            (const __attribute__((address_space(1))) void*)(src1 + (ck_) * 64),\
            (__attribute__((address_space(3))) void*)(b_ + 8192), 16, 0, 0);   \
    }

    // ---- B geometry: fragment-major, nf = wv*2+fn (verified r6/r8) ----
    const short8* wb = (const short8*)(WF) + ((size_t)(wv * 2) * 64 + lane);
#define LDB(dst, g_)                                                           \
    {                                                                          \
        _Pragma("unroll")                                                      \
        for (int fn = 0; fn < 2; ++fn)                                         \
            dst[fn] = wb[(g_) * 1024 + fn * 64];                               \
    }

    // ---- A-frag: row rg*32+(l&31), floats kt4*16+(l>>5)*8 (v13-verified) ----
    const int arow = (lane & 31) * 256;
    const int aq32 = (lane >> 5) << 5;
    const int aswz = (lane & 15) << 4;

#define LDA_CVT(dst, ab_, kt4_)                                                \
    {                                                                          \
        _Pragma("unroll")                                                      \
        for (int rg = 0; rg < 2; ++rg) {                                       \
            const char* p_  = (ab_) + rg * 8192 + arow;                        \
            const int  blo_ = (((kt4_) << 6) + aq32) ^ aswz;                   \
            f32x4 lo_ = *(const f32x4*)(p_ + blo_);                            \
            f32x4 hi_ = *(const f32x4*)(p_ + (blo_ ^ 16));                     \
            u32 w0_, w1_, w2_, w3_;                                            \
            asm("v_cvt_pk_bf16_f32 %0, %1, %2" : "=v"(w0_)                     \
                : "v"(lo_[0]), "v"(lo_[1]));                                   \
            asm("v_cvt_pk_bf16_f32 %0, %1, %2" : "=v"(w1_)                     \
                : "v"(lo_[2]), "v"(lo_[3]));                                   \
            asm("v_cvt_pk_bf16_f32 %0, %1, %2" : "=v"(w2_)                     \
                : "v"(hi_[0]), "v"(hi_[1]));                                   \
            asm("v_cvt_pk_bf16_f32 %0, %1, %2" : "=v"(w3_)                     \
                : "v"(hi_[2]), "v"(hi_[3]));                                   \
            union { u32 w[4]; short8 v; } pk_;                                 \
            pk_.w[0] = w0_; pk_.w[1] = w1_; pk_.w[2] = w2_; pk_.w[3] = w3_;    \
            dst[rg] = pk_.v;                                                   \
        }                                                                      \
    }

    // ---- bias -> accumulator init ----
    f32x16 acc[2][2];
#pragma unroll
    for (int fn = 0; fn < 2; ++fn) {
        const float bv = bias[wv * 64 + fn * 32 + (lane & 31)];
#pragma unroll
        for (int rg = 0; rg < 2; ++rg)
#pragma unroll
            for (int r = 0; r < 16; ++r) acc[rg][fn][r] = bv;
    }

    // ---- prologue: two chunks of DMA in flight ----
    ISSUE_DMA(0);
    ISSUE_DMA(1);

    short8 bf[2][2];
#pragma unroll
    for (int ck = 0; ck < NCH; ++ck) {
        // chunk-B head loads (before the wait; FIFO-newest)
        LDB(bf[0], ck * 4 + 0);
        LDB(bf[1], ck * 4 + 1);
        __builtin_amdgcn_sched_barrier(0);
        // retire DMA(ck). outstanding here (steady): DMA(ck+1):2 + B:4 = 6.
        // (DMA(ck) itself was already forced home by chunk ck-1's B use; the
        //  explicit wait is then a no-op -- kept for the ck<=1 boundary.)
        if (ck < NCH - 1) asm volatile("s_waitcnt vmcnt(6)" ::: "memory");
        else              asm volatile("s_waitcnt vmcnt(4)" ::: "memory");
        __builtin_amdgcn_sched_barrier(0);
        __builtin_amdgcn_s_barrier();
        __builtin_amdgcn_sched_barrier(0);

        const char* ab = smem + (ck & 3) * BUFB;
        short8 af[2];
#pragma unroll
        for (int kt4 = 0; kt4 < 4; ++kt4) {
            LDA_CVT(af, ab, kt4);
            __builtin_amdgcn_s_setprio(1);
#pragma unroll
            for (int rg = 0; rg < 2; ++rg)
#pragma unroll
                for (int fn = 0; fn < 2; ++fn)
                    acc[rg][fn] = __builtin_amdgcn_mfma_f32_32x32x16_bf16(
                        af[rg], bf[kt4 & 1][fn], acc[rg][fn], 0, 0, 0);
            __builtin_amdgcn_s_setprio(0);
            if (kt4 < 2) LDB(bf[kt4 & 1], ck * 4 + kt4 + 2);
            // (2) DMA for ck+2 issued only after ALL this chunk's B loads,
            // so consuming g2/g3 never forces it to retire early.
            if (kt4 == 1 && ck + 2 < NCH) {
                __builtin_amdgcn_sched_barrier(0);
                ISSUE_DMA(ck + 2);
                __builtin_amdgcn_sched_barrier(0);
            }
        }
    }
#undef ISSUE_DMA
#undef LDB
#undef LDA_CVT

    // ---- epilogue: direct stores (bias already in acc) ----
    // C/D: col = lane&31, row = (r&3) + 8*(r>>2) + 4*(lane>>5)
    const int c     = lane & 31;
    const int rbase = (lane >> 5) << 2;
#pragma unroll
    for (int rg = 0; rg < 2; ++rg)
#pragma unroll
        for (int fn = 0; fn < 2; ++fn)
#pragma unroll
            for (int r = 0; r < 16; ++r) {
                const int row = rg * 32 + (r & 3) + 8 * (r >> 2) + rbase;
                out[(size_t)(m0 + row) * OUT_F + wv * 64 + fn * 32 + c] =
                    acc[rg][fn][r];
            }
}

extern "C" void kernel_launch(void* const* d_in, const int* in_sizes, int n_in,
                              void* d_out, int out_size, void* d_ws, size_t ws_size,
                              hipStream_t stream) {
    const float* X    = (const float*)d_in[0];
    const float* W    = (const float*)d_in[1];
    const float* bias = (const float*)d_in[2];
    float* o          = (float*)d_out;
    unsigned short* wf = (unsigned short*)d_ws; // 512KB fragment-major binarized W

    hipLaunchKernelGGL(prep_w, dim3(128), dim3(256), 0, stream, W, wf);
    hipLaunchKernelGGL(gemm_bin, dim3(BATCH / BM), dim3(512), 0, stream,
                       X, wf, bias, o);
}

// Round 20
// 128.271 us; speedup vs baseline: 2.5700x; 1.0817x over previous
//
#include <hip/hip_runtime.h>
#include <stdint.h>

// LinearBin: out = x @ sign(W)^T + bias   (B=131072, IN=OUT=512, fp32)
// v20: exploit the binary weight structure. W packed to 1 bit/elem (32KB,
//      L2-resident); each wave holds its whole B K-panel in 16 VGPRs and
//      expands to bf16 fragments in-register (multiply-spread, ~16 VALU/frag)
//      in the DMA-wait shadow. K-loop VMEM = x-DMA stream ONLY -> exact
//      vmcnt(4) with a true 3-chunk (~1200cy) lead covering HBM misses.
//      Geometry: BM=32, 4-wave blocks, wave tile 32x64, 4x8KB ring (32KB),
//      4 blocks/CU, XCD-paired col-halves for x L2 reuse.

#define BATCH   131072
#define IN_F    512
#define OUT_F   512
#define BM      32
#define NCH     8             // K-chunks of 64 floats (4 mfma k-steps each)
#define BUFB    8192          // bytes per ring buffer

using f32x4  = __attribute__((ext_vector_type(4))) float;
using f32x16 = __attribute__((ext_vector_type(16))) float;
using short8 = __attribute__((ext_vector_type(8))) short;
using u32    = uint32_t;
using u64    = unsigned long long;

// ---------------- prep: pack sign bits ----------------
// wp[(nf*64+l)*8 + q], byte b (kt=4q+b), bit j =
//   (W[nf*32+(l&31)][kt*16 + (l>>5)*8 + j] < 0)
// matches the verified r6/r8 B-fragment layout, 1 bit per element. 32KB.
__global__ void prep_wbits(const float* __restrict__ W, u32* __restrict__ wp) {
    int t = blockIdx.x * blockDim.x + threadIdx.x;  // 1024 threads
    int l  = t & 63;
    int nf = t >> 6;
    const float* row = W + (size_t)(nf * 32 + (l & 31)) * IN_F + ((l >> 5) << 3);
#pragma unroll
    for (int q = 0; q < 8; ++q) {
        u32 word = 0;
#pragma unroll
        for (int b = 0; b < 4; ++b) {
            const float* p = row + (q * 4 + b) * 16;
            u32 by = 0;
#pragma unroll
            for (int j = 0; j < 8; ++j)
                by |= (p[j] >= 0.0f ? 0u : 1u) << j;
            word |= by << (8 * b);
        }
        wp[(size_t)t * 8 + q] = word;
    }
}

// bits (low 8 of bb) -> short8 of bf16 +/-1. Multiply-spread: bit k of a
// nibble lands at u64 position 15k+15 (no carries: shifts spaced 15 > 3).
__device__ __forceinline__ short8 expB(u32 bb) {
    const u64 MUL = 0x1000200040008000ull;
    const u64 MSK = 0x8000800080008000ull;
    const u64 ONE = 0x3F803F803F803F80ull;
    u64 lo = ((u64)(bb & 0xFu) * MUL) & MSK;
    u64 hi = ((u64)((bb >> 4) & 0xFu) * MUL) & MSK;
    union { u64 d[2]; short8 v; } pk;
    pk.d[0] = ONE | lo;
    pk.d[1] = ONE | hi;
    return pk.v;
}

// ---------------- GEMM ----------------
__global__ __launch_bounds__(256, 4) void gemm_bin(
    const float* __restrict__ X, const u32* __restrict__ WP,
    const float* __restrict__ bias, float* __restrict__ out) {

    // ring of 4 fp32 chunks: [32 rows][256B], 16B slots XOR-swizzled by row&15
    __shared__ __align__(16) char smem[4 * BUFB];   // 32KB -> 4 blocks/CU

    const int tid  = threadIdx.x;
    const int lane = tid & 63;
    const int wv   = tid >> 6;              // 0..3 -> 64-col slice

    // XCD pairing: q=0/1 col-halves of a strip are dispatch-adjacent per XCD
    const int d     = blockIdx.x;           // grid = 8192
    const int xcd   = d & 7;
    const int i     = d >> 3;
    const int q     = i & 1;
    const int strip = (i >> 1) * 8 + xcd;   // bijective: 512*8 = 4096 strips
    const int m0    = strip * BM;
    const int col0  = q * 256 + wv * 64;

    // ---- DMA source geometry (2 x 16B per thread per chunk) ----
    const int dr   = wv * 4 + (lane >> 4);  // rows 0..15 (+16 for instr1)
    const int ds4  = ((lane & 15) ^ (dr & 15)) << 2;
    const float* src0 = X + (size_t)(m0 + dr) * IN_F + ds4;
    const float* src1 = src0 + (size_t)16 * IN_F;  // (dr+16)&15 == dr&15

#define ISSUE_DMA(ck_)                                                         \
    {                                                                          \
        char* b_ = smem + ((ck_) & 3) * BUFB + wv * 1024;                      \
        __builtin_amdgcn_global_load_lds(                                      \
            (const __attribute__((address_space(1))) void*)(src0 + (ck_) * 64),\
            (__attribute__((address_space(3))) void*)(b_), 16, 0, 0);          \
        __builtin_amdgcn_global_load_lds(                                      \
            (const __attribute__((address_space(1))) void*)(src1 + (ck_) * 64),\
            (__attribute__((address_space(3))) void*)(b_ + 4096), 16, 0, 0);   \
    }

    // ---- load the wave's whole B-bit panel: 16 u32 (2 nf x 8) ----
    const u32* wpp = WP + (((size_t)(q * 8 + wv * 2) * 64 + lane) << 3);
    uint4 a0 = *(const uint4*)(wpp);
    uint4 a1 = *(const uint4*)(wpp + 4);
    uint4 b0 = *(const uint4*)(wpp + 512);   // nf+1 is +64*8 u32
    uint4 b1 = *(const uint4*)(wpp + 516);
    __builtin_amdgcn_sched_barrier(0);       // pin: wp loads oldest in FIFO

    // ---- prologue: 3 chunks of DMA in flight ----
    ISSUE_DMA(0);
    ISSUE_DMA(1);
    ISSUE_DMA(2);
    __builtin_amdgcn_sched_barrier(0);

    const u32 w0[8] = {a0.x, a0.y, a0.z, a0.w, a1.x, a1.y, a1.z, a1.w};
    const u32 w1[8] = {b0.x, b0.y, b0.z, b0.w, b1.x, b1.y, b1.z, b1.w};

    // ---- A-frag geometry (16-slot swizzle, verified 0-conflict) ----
    const int arow = (lane & 31) * 256;
    const int aq32 = (lane >> 5) << 5;
    const int aswz = (lane & 15) << 4;

    // ---- bias -> accumulator init ----
    f32x16 acc[2];
#pragma unroll
    for (int fn = 0; fn < 2; ++fn) {
        const float bv = bias[col0 + fn * 32 + (lane & 31)];
#pragma unroll
        for (int r = 0; r < 16; ++r) acc[fn][r] = bv;
    }

#pragma unroll
    for (int ck = 0; ck < NCH; ++ck) {
        // expand this chunk's 8 B-frags from register bits (DMA-wait shadow)
        short8 bf[4][2];
#pragma unroll
        for (int k4 = 0; k4 < 4; ++k4) {
            const int kt = ck * 4 + k4;
            bf[k4][0] = expB(w0[kt >> 2] >> ((kt & 3) * 8));
            bf[k4][1] = expB(w1[kt >> 2] >> ((kt & 3) * 8));
        }
        __builtin_amdgcn_sched_barrier(0);
        // retire exactly DMA(ck); D(ck+1),D(ck+2) stay in flight
        if (ck < NCH - 2)       asm volatile("s_waitcnt vmcnt(4)" ::: "memory");
        else if (ck == NCH - 2) asm volatile("s_waitcnt vmcnt(2)" ::: "memory");
        else                    asm volatile("s_waitcnt vmcnt(0)" ::: "memory");
        __builtin_amdgcn_sched_barrier(0);
        __builtin_amdgcn_s_barrier();
        __builtin_amdgcn_sched_barrier(0);
        if (ck + 3 < NCH) ISSUE_DMA(ck + 3);  // buf (ck-1)&3 freed by barrier

        const char* ab = smem + (ck & 3) * BUFB;
#pragma unroll
        for (int k4 = 0; k4 < 4; ++k4) {
            const int blo = ((k4 << 6) + aq32) ^ aswz;
            f32x4 lo = *(const f32x4*)(ab + arow + blo);
            f32x4 hi = *(const f32x4*)(ab + arow + (blo ^ 16));
            u32 c0, c1, c2, c3;
            asm("v_cvt_pk_bf16_f32 %0, %1, %2" : "=v"(c0) : "v"(lo[0]), "v"(lo[1]));
            asm("v_cvt_pk_bf16_f32 %0, %1, %2" : "=v"(c1) : "v"(lo[2]), "v"(lo[3]));
            asm("v_cvt_pk_bf16_f32 %0, %1, %2" : "=v"(c2) : "v"(hi[0]), "v"(hi[1]));
            asm("v_cvt_pk_bf16_f32 %0, %1, %2" : "=v"(c3) : "v"(hi[2]), "v"(hi[3]));
            union { u32 w[4]; short8 v; } pk;
            pk.w[0] = c0; pk.w[1] = c1; pk.w[2] = c2; pk.w[3] = c3;
            __builtin_amdgcn_s_setprio(1);
            acc[0] = __builtin_amdgcn_mfma_f32_32x32x16_bf16(pk.v, bf[k4][0], acc[0], 0, 0, 0);
            acc[1] = __builtin_amdgcn_mfma_f32_32x32x16_bf16(pk.v, bf[k4][1], acc[1], 0, 0, 0);
            __builtin_amdgcn_s_setprio(0);
        }
    }
#undef ISSUE_DMA

    // ---- epilogue: direct stores (bias already in acc) ----
    // C/D: col = lane&31, row = (r&3) + 8*(r>>2) + 4*(lane>>5)
    const int c     = lane & 31;
    const int rbase = (lane >> 5) << 2;
#pragma unroll
    for (int fn = 0; fn < 2; ++fn)
#pragma unroll
        for (int r = 0; r < 16; ++r) {
            const int row = (r & 3) + 8 * (r >> 2) + rbase;
            out[(size_t)(m0 + row) * OUT_F + col0 + fn * 32 + c] = acc[fn][r];
        }
}

extern "C" void kernel_launch(void* const* d_in, const int* in_sizes, int n_in,
                              void* d_out, int out_size, void* d_ws, size_t ws_size,
                              hipStream_t stream) {
    const float* X    = (const float*)d_in[0];
    const float* W    = (const float*)d_in[1];
    const float* bias = (const float*)d_in[2];
    float* o          = (float*)d_out;
    u32* wp           = (u32*)d_ws;   // 32KB packed sign bits

    hipLaunchKernelGGL(prep_wbits, dim3(4), dim3(256), 0, stream, W, wp);
    hipLaunchKernelGGL(gemm_bin, dim3(2 * BATCH / BM), dim3(256), 0, stream,
                       X, wp, bias, o);
}

// Round 21
// 127.789 us; speedup vs baseline: 2.5797x; 1.0038x over previous
//
#include <hip/hip_runtime.h>
#include <stdint.h>

// LinearBin: out = x @ sign(W)^T + bias   (B=131072, IN=OUT=512, fp32)
// v21: v20 (128.3us) with x staged ONCE. Block = 512 thr / 8 waves covering
//      all 512 cols (wave tile 32x64 unchanged); per-wave profile identical
//      to v20 (16 bit-VGPRs, 32 AGPR acc) -> same 4 waves/SIMD, 2 blocks/CU.
//      DMA = 1 instr/wave/chunk (512thr x 16B = 8KB chunk); cvt work and
//      L2 x-traffic halve. Pure-DMA FIFO, lead 3 (vmcnt 2/1/0), D(ck+3)
//      issued post-barrier into the buffer that barrier freed (v20 pattern).

#define BATCH   131072
#define IN_F    512
#define OUT_F   512
#define BM      32
#define NCH     8             // K-chunks of 64 floats (4 mfma k-steps each)
#define BUFB    8192          // bytes per ring buffer (32 rows x 256B)

using f32x4  = __attribute__((ext_vector_type(4))) float;
using f32x16 = __attribute__((ext_vector_type(16))) float;
using short8 = __attribute__((ext_vector_type(8))) short;
using u32    = uint32_t;
using u64    = unsigned long long;

// ---------------- prep: pack sign bits (verified v20) ----------------
// wp[(nf*64+l)*8 + q], byte b (kt=4q+b), bit j =
//   (W[nf*32+(l&31)][kt*16 + (l>>5)*8 + j] < 0)
__global__ void prep_wbits(const float* __restrict__ W, u32* __restrict__ wp) {
    int t = blockIdx.x * blockDim.x + threadIdx.x;  // 1024 threads
    int l  = t & 63;
    int nf = t >> 6;
    const float* row = W + (size_t)(nf * 32 + (l & 31)) * IN_F + ((l >> 5) << 3);
#pragma unroll
    for (int q = 0; q < 8; ++q) {
        u32 word = 0;
#pragma unroll
        for (int b = 0; b < 4; ++b) {
            const float* p = row + (q * 4 + b) * 16;
            u32 by = 0;
#pragma unroll
            for (int j = 0; j < 8; ++j)
                by |= (p[j] >= 0.0f ? 0u : 1u) << j;
            word |= by << (8 * b);
        }
        wp[(size_t)t * 8 + q] = word;
    }
}

// bits (low 8 of bb) -> short8 of bf16 +/-1 (multiply-spread, verified v20)
__device__ __forceinline__ short8 expB(u32 bb) {
    const u64 MUL = 0x1000200040008000ull;
    const u64 MSK = 0x8000800080008000ull;
    const u64 ONE = 0x3F803F803F803F80ull;
    u64 lo = ((u64)(bb & 0xFu) * MUL) & MSK;
    u64 hi = ((u64)((bb >> 4) & 0xFu) * MUL) & MSK;
    union { u64 d[2]; short8 v; } pk;
    pk.d[0] = ONE | lo;
    pk.d[1] = ONE | hi;
    return pk.v;
}

// ---------------- GEMM ----------------
__global__ __launch_bounds__(512, 4) void gemm_bin(
    const float* __restrict__ X, const u32* __restrict__ WP,
    const float* __restrict__ bias, float* __restrict__ out) {

    // ring of 4 fp32 chunks: [32 rows][256B], 16B slots XOR-swizzled by row&15
    __shared__ __align__(16) char smem[4 * BUFB];   // 32KB -> 2 blocks/CU

    const int tid  = threadIdx.x;
    const int lane = tid & 63;
    const int wv   = tid >> 6;              // 0..7 -> 64-col strip
    const int m0   = blockIdx.x * BM;       // grid = 4096
    const int col0 = wv * 64;

    // ---- load the wave's B-bit panel first (FIFO-oldest): 16 u32 ----
    const u32* wpp = WP + (((size_t)(wv * 2) * 64 + lane) << 3);
    uint4 a0 = *(const uint4*)(wpp);
    uint4 a1 = *(const uint4*)(wpp + 4);
    uint4 b0 = *(const uint4*)(wpp + 512);   // nf+1 = +64*8 u32
    uint4 b1 = *(const uint4*)(wpp + 516);
    __builtin_amdgcn_sched_barrier(0);

    // ---- bias -> acc init (bias load retires before any DMA is issued) ----
    f32x16 acc[2];
#pragma unroll
    for (int fn = 0; fn < 2; ++fn) {
        const float bv = bias[col0 + fn * 32 + (lane & 31)];
#pragma unroll
        for (int r = 0; r < 16; ++r) acc[fn][r] = bv;
    }
    __builtin_amdgcn_sched_barrier(0);

    const u32 w0[8] = {a0.x, a0.y, a0.z, a0.w, a1.x, a1.y, a1.z, a1.w};
    const u32 w1[8] = {b0.x, b0.y, b0.z, b0.w, b1.x, b1.y, b1.z, b1.w};

    // ---- DMA geometry: 1 x 16B per thread per chunk (512 thr = 8KB) ----
    // lane l of wave wv -> row wv*4 + (l>>4), slot l&15; pre-swizzled source.
    const int dr   = wv * 4 + (lane >> 4);
    const int ds4  = ((lane & 15) ^ (dr & 15)) << 2;
    const float* srcx = X + (size_t)(m0 + dr) * IN_F + ds4;

#define ISSUE_DMA(ck_)                                                         \
    {                                                                          \
        char* b_ = smem + ((ck_) & 3) * BUFB + wv * 1024;                      \
        __builtin_amdgcn_global_load_lds(                                      \
            (const __attribute__((address_space(1))) void*)(srcx + (ck_) * 64),\
            (__attribute__((address_space(3))) void*)(b_), 16, 0, 0);          \
    }

    // ---- prologue: 3 chunks of DMA in flight ----
    ISSUE_DMA(0);
    ISSUE_DMA(1);
    ISSUE_DMA(2);
    __builtin_amdgcn_sched_barrier(0);

    // ---- A-frag geometry (16-slot swizzle, verified 0-conflict) ----
    const int arow = (lane & 31) * 256;
    const int aq32 = (lane >> 5) << 5;
    const int aswz = (lane & 15) << 4;

#pragma unroll
    for (int ck = 0; ck < NCH; ++ck) {
        // expand this chunk's 8 B-frags from register bits (DMA-wait shadow)
        short8 bf[4][2];
#pragma unroll
        for (int k4 = 0; k4 < 4; ++k4) {
            const int kt = ck * 4 + k4;
            bf[k4][0] = expB(w0[kt >> 2] >> ((kt & 3) * 8));
            bf[k4][1] = expB(w1[kt >> 2] >> ((kt & 3) * 8));
        }
        __builtin_amdgcn_sched_barrier(0);
        // retire exactly DMA(ck); ck+1, ck+2 stay in flight
        if (ck < NCH - 2)       asm volatile("s_waitcnt vmcnt(2)" ::: "memory");
        else if (ck == NCH - 2) asm volatile("s_waitcnt vmcnt(1)" ::: "memory");
        else                    asm volatile("s_waitcnt vmcnt(0)" ::: "memory");
        __builtin_amdgcn_sched_barrier(0);
        __builtin_amdgcn_s_barrier();
        __builtin_amdgcn_sched_barrier(0);
        if (ck + 3 < NCH) ISSUE_DMA(ck + 3);  // buf (ck-1)&3 freed by barrier

        const char* ab = smem + (ck & 3) * BUFB;
#pragma unroll
        for (int k4 = 0; k4 < 4; ++k4) {
            const int blo = ((k4 << 6) + aq32) ^ aswz;
            f32x4 lo = *(const f32x4*)(ab + arow + blo);
            f32x4 hi = *(const f32x4*)(ab + arow + (blo ^ 16));
            u32 c0, c1, c2, c3;
            asm("v_cvt_pk_bf16_f32 %0, %1, %2" : "=v"(c0) : "v"(lo[0]), "v"(lo[1]));
            asm("v_cvt_pk_bf16_f32 %0, %1, %2" : "=v"(c1) : "v"(lo[2]), "v"(lo[3]));
            asm("v_cvt_pk_bf16_f32 %0, %1, %2" : "=v"(c2) : "v"(hi[0]), "v"(hi[1]));
            asm("v_cvt_pk_bf16_f32 %0, %1, %2" : "=v"(c3) : "v"(hi[2]), "v"(hi[3]));
            union { u32 w[4]; short8 v; } pk;
            pk.w[0] = c0; pk.w[1] = c1; pk.w[2] = c2; pk.w[3] = c3;
            __builtin_amdgcn_s_setprio(1);
            acc[0] = __builtin_amdgcn_mfma_f32_32x32x16_bf16(pk.v, bf[k4][0], acc[0], 0, 0, 0);
            acc[1] = __builtin_amdgcn_mfma_f32_32x32x16_bf16(pk.v, bf[k4][1], acc[1], 0, 0, 0);
            __builtin_amdgcn_s_setprio(0);
        }
    }
#undef ISSUE_DMA

    // ---- epilogue: direct stores (bias already in acc) ----
    // C/D: col = lane&31, row = (r&3) + 8*(r>>2) + 4*(lane>>5)
    const int c     = lane & 31;
    const int rbase = (lane >> 5) << 2;
#pragma unroll
    for (int fn = 0; fn < 2; ++fn)
#pragma unroll
        for (int r = 0; r < 16; ++r) {
            const int row = (r & 3) + 8 * (r >> 2) + rbase;
            out[(size_t)(m0 + row) * OUT_F + col0 + fn * 32 + c] = acc[fn][r];
        }
}

extern "C" void kernel_launch(void* const* d_in, const int* in_sizes, int n_in,
                              void* d_out, int out_size, void* d_ws, size_t ws_size,
                              hipStream_t stream) {
    const float* X    = (const float*)d_in[0];
    const float* W    = (const float*)d_in[1];
    const float* bias = (const float*)d_in[2];
    float* o          = (float*)d_out;
    u32* wp           = (u32*)d_ws;   // 32KB packed sign bits

    hipLaunchKernelGGL(prep_wbits, dim3(4), dim3(256), 0, stream, W, wp);
    hipLaunchKernelGGL(gemm_bin, dim3(BATCH / BM), dim3(512), 0, stream,
                       X, wp, bias, o);
}